// Round 12
// baseline (273.813 us; speedup 1.0000x reference)
//
#include <hip/hip_runtime.h>
#include <float.h>
#include <math.h>

// Problem constants (from reference setup_inputs)
#define LQ   512
#define LL   4096      // key length
#define DD   64        // d_qk == d_v
#define KEEP 32        // MAX_SET_SIZE
#define NB   8         // batches
#define NROWS (NB * LQ)    // 4096 flat query rows

// ---- ws layout (floats) -----------------------------------------------------
// scores : [NROWS][LL] fp32                67.11 MB
// VT     : [NB][DD][LL] bf16                4.19 MB
// pcnt   : [NROWS] fp32 counts (atomic)     0.02 MB (region sized 4x, proven)
#define WS_VT    (NROWS * LL)                    // 16,777,216
#define WS_PC    (WS_VT + (NB * DD * LL) / 2)    // 17,825,792
#define WS_TOTAL (WS_PC + 4 * NROWS)             // 17,842,176 floats = 71.37 MB

#define MASKED_KEY 0x00800000u              // order-key of -FLT_MAX

typedef short  bf16x8 __attribute__((ext_vector_type(8)));
typedef float  f32x4  __attribute__((ext_vector_type(4)));

__device__ __forceinline__ float dot4(float4 a, float4 b) {
    return a.x * b.x + a.y * b.y + a.z * b.z + a.w * b.w;
}
__device__ __forceinline__ unsigned short f2bf(float f) {
    unsigned int u = __float_as_uint(f);
    return (unsigned short)((u + 0x7FFFu + ((u >> 16) & 1u)) >> 16);   // RNE
}

// ============================================================================
// P0: v[b][l][d] fp32 -> VT[b][d][l] bf16 (LDS tile transpose) + ZERO out and
// pcnt (absorbs memset nodes). VERBATIM R11 (control).
// ============================================================================
#define TP_LB 256
__global__ __launch_bounds__(256) void k_vt(
    const float* __restrict__ v, unsigned short* __restrict__ vt,
    float* __restrict__ out, float* __restrict__ pcnt)
{
    __shared__ unsigned short tile[DD][TP_LB + 8];   // +8 ushorts: bank de-phase
    const int t  = threadIdx.x;
    const int b  = blockIdx.x >> 4;                  // 16 blocks per batch
    const int l0 = (blockIdx.x & 15) * TP_LB;

    // ---- zeroing (replaces memset nodes): 128 blocks cover out + pcnt ------
    {
        float4 z4 = {0.f, 0.f, 0.f, 0.f};
        float4* oz = reinterpret_cast<float4*>(out);  // 65536 float4 total
        oz[blockIdx.x * 512 + t]       = z4;
        oz[blockIdx.x * 512 + 256 + t] = z4;
        if (t < 32) pcnt[blockIdx.x * 32 + t] = 0.f;  // 128*32 = 4096
    }

    const float4* vg = reinterpret_cast<const float4*>(v + ((size_t)b * LL + l0) * DD);
    #pragma unroll
    for (int i = 0; i < 16; ++i) {
        int j = t + 256 * i;                         // f4 index: l = j>>4, dq = (j&15)*4
        float4 f = vg[j];
        int l = j >> 4, dq = (j & 15) * 4;
        tile[dq + 0][l] = f2bf(f.x);
        tile[dq + 1][l] = f2bf(f.y);
        tile[dq + 2][l] = f2bf(f.z);
        tile[dq + 3][l] = f2bf(f.w);
    }
    __syncthreads();
    const int d = t >> 2, seg = t & 3;               // 64 ushorts per thread
    const uint4* src = reinterpret_cast<const uint4*>(&tile[d][seg * 64]);
    uint4* dst = reinterpret_cast<uint4*>(vt + ((size_t)b * DD + d) * LL + l0 + seg * 64);
    #pragma unroll
    for (int i = 0; i < 8; ++i) dst[i] = src[i];
}

// ============================================================================
// K1 v4: register-K scores + fused masked-mean partial.
// Two changes vs R10/R11 (both counter-driven):
//  (a) sums padded [16][17]: kills the 1.05M SQ_LDS_BANK_CONFLICT from the
//      power-of-2-strided MFMA-acc spill writes.
//  (b) kreg (K row, 16 dwordx4/lane, ~900cy HBM) issued BEFORE the mean
//      phase: the loads fly under the mean's MFMA/VT/ballot work and the
//      compiler's vmcnt(0) barrier-drain finds them arrived, instead of
//      every wave stalling cold at scoring start. Costs ~64 VGPR of live
//      range across the mean phase (56 -> ~120); measured occupancy was
//      ~3 waves/SIMD so the 4-waves/SIMD VGPR cap should not bind.
// ============================================================================
__global__ __launch_bounds__(256) void k_scores(
    const float* __restrict__ q,
    const float* __restrict__ kmat,
    const int*   __restrict__ mask,
    const unsigned short* __restrict__ vt,
    float*       __restrict__ ws_sc,
    float*       __restrict__ out,
    float*       __restrict__ pcnt)
{
    __shared__ unsigned long long bits64[4][16];     // [wave][row] 512 B
    __shared__ float sums[4][4][16][17];             // padded: bank de-phase
    __shared__ float cnt_s[4][16];

    const int t    = threadIdx.x;
    const int wave = t >> 6;
    const int lane = t & 63;
    const int lc   = blockIdx.x & 15;                // l-chunk -> XCD spread (%8)
    const int rg   = blockIdx.x >> 4;                // row-group 0..255
    const int n0   = rg * 16;
    const int b    = n0 / LQ;
    const int l    = lc * 256 + wave * 64 + lane;    // this lane's l

    // ---- mask prefetch: 16 rows, coalesced dword each -----------------------
    int mreg[16];
    #pragma unroll
    for (int p = 0; p < 16; ++p)
        mreg[p] = mask[(size_t)(n0 + p) * LL + l];

    // ---- K row -> 64 VGPR, ISSUED EARLY (hidden under the mean phase) ------
    const float4* kr = reinterpret_cast<const float4*>(kmat + ((size_t)b * LL + l) * DD);
    float4 kreg[16];
    #pragma unroll
    for (int i = 0; i < 16; ++i) kreg[i] = kr[i];

    // ---- ballots -> per-row 64-bit masks of this wave's 64 l ---------------
    unsigned long long bl[16];
    #pragma unroll
    for (int p = 0; p < 16; ++p) bl[p] = __ballot(mreg[p] != 0);
    if (lane == 0) {
        #pragma unroll
        for (int p = 0; p < 16; ++p) bits64[wave][p] = bl[p];
    }
    __asm__ volatile("s_waitcnt lgkmcnt(0)" ::: "memory");

    // ---- fused mean partial: 8 MFMA off LDS bits + VT ----------------------
    {
        const int row_a = lane & 15;                 // MFMA m / B n index
        const int chunk = lane >> 4;                 // k-quad
        const unsigned char* bb =
            reinterpret_cast<const unsigned char*>(&bits64[wave][row_a]);
        const unsigned short* vtb =
            vt + (size_t)b * DD * LL + lc * 256 + wave * 64 + chunk * 8;

        f32x4 acc[4];
        #pragma unroll
        for (int dt = 0; dt < 4; ++dt) acc[dt] = (f32x4){0.f, 0.f, 0.f, 0.f};

        #pragma unroll
        for (int s = 0; s < 2; ++s) {                // K-step: 32 l each
            const unsigned int byte = bb[s * 4 + chunk];
            unsigned int pk[4];
            pk[0] = ((byte & 1u)   ? 0x3F80u : 0u) | ((byte & 2u)   ? 0x3F800000u : 0u);
            pk[1] = ((byte & 4u)   ? 0x3F80u : 0u) | ((byte & 8u)   ? 0x3F800000u : 0u);
            pk[2] = ((byte & 16u)  ? 0x3F80u : 0u) | ((byte & 32u)  ? 0x3F800000u : 0u);
            pk[3] = ((byte & 64u)  ? 0x3F80u : 0u) | ((byte & 128u) ? 0x3F800000u : 0u);
            bf16x8 afrag = *reinterpret_cast<bf16x8*>(pk);
            #pragma unroll
            for (int dt = 0; dt < 4; ++dt) {
                bf16x8 bfrag = *reinterpret_cast<const bf16x8*>(
                    vtb + (size_t)(dt * 16 + row_a) * LL + s * 32);
                acc[dt] = __builtin_amdgcn_mfma_f32_16x16x32_bf16(afrag, bfrag, acc[dt], 0, 0, 0);
            }
        }
        #pragma unroll
        for (int dt = 0; dt < 4; ++dt)
            #pragma unroll
            for (int r = 0; r < 4; ++r)
                sums[wave][dt][chunk * 4 + r][row_a] = acc[dt][r];
        if (lane < 16)
            cnt_s[wave][lane] = (float)__popcll(bits64[wave][lane]);
    }
    __syncthreads();

    // ---- combine 4 waves + atomic partial accumulate ------------------------
    {
        const int d = t & 63, rgrp = t >> 6;
        #pragma unroll
        for (int rr = 0; rr < 4; ++rr) {
            const int row = rgrp * 4 + rr;
            float s = sums[0][d >> 4][row][d & 15] + sums[1][d >> 4][row][d & 15]
                    + sums[2][d >> 4][row][d & 15] + sums[3][d >> 4][row][d & 15];
            atomicAdd(&out[(size_t)(n0 + row) * DD + d], s);
        }
        if (t < 16) {
            float c = cnt_s[0][t] + cnt_s[1][t] + cnt_s[2][t] + cnt_s[3][t];
            atomicAdd(&pcnt[n0 + t], c);
        }
    }

    // ---- scoring: register-K, R9 proven form (kreg already resident) --------
    const int qb = __builtin_amdgcn_readfirstlane(n0 * DD);
    #pragma unroll
    for (int p = 0; p < 16; ++p) {
        const float4* qp = reinterpret_cast<const float4*>(q + qb + p * DD);
        float ax = 0.f, ay = 0.f, az = 0.f, aw = 0.f;
        #pragma unroll
        for (int i = 0; i < 16; ++i) {
            float4 qv = qp[i];                       // wave-uniform -> s_load
            ax = fmaf(qv.x, kreg[i].x, ax);
            ay = fmaf(qv.y, kreg[i].y, ay);
            az = fmaf(qv.z, kreg[i].z, az);
            aw = fmaf(qv.w, kreg[i].w, aw);
        }
        float acc = ax + ay + az + aw;
        ws_sc[(size_t)(n0 + p) * LL + l] = mreg[p] ? acc * 0.125f : -FLT_MAX;
    }
}

// ============================================================================
// K2: per-wave exact radix top-32 — VERBATIM R10/R11 (control).
// ============================================================================
__global__ __launch_bounds__(256, 3) void k_select(
    const float* __restrict__ vmat,
    const float* __restrict__ ws,
    const float* __restrict__ pcnt,
    float*       __restrict__ out)
{
    __shared__ unsigned int hist[4][256];
    __shared__ unsigned int selKey[4][KEEP];
    __shared__ int          selIdx[4][KEEP];
    __shared__ float        wsel[4][KEEP];
    __shared__ int          selCnt[4], eqCnt[4];

    const int t    = threadIdx.x;
    const int wave = t >> 6;
    const int lane = t & 63;
    const int row  = blockIdx.x * 4 + wave;
    const int b    = row / LQ;

    // ---- mean finalize: sum (atomic-accumulated) / clip(count,1) ------------
    float o = out[(size_t)row * DD + lane];
    {
        float cc = pcnt[row];
        if (cc < 1.f) cc = 1.f;
        o /= cc;
    }

    // ---- load row scores -> order-preserving uint keys (64 VGPRs) -----------
    unsigned int key[64];
    {
        const float4* sg = reinterpret_cast<const float4*>(ws) + (size_t)row * (LL / 4);
        #pragma unroll
        for (int i = 0; i < 16; ++i) {
            float4 f = sg[lane + 64 * i];
            float vals[4] = { f.x, f.y, f.z, f.w };
            #pragma unroll
            for (int c = 0; c < 4; ++c) {
                unsigned int u = __float_as_uint(vals[c]);
                key[4 * i + c] = ((int)u < 0) ? ~u : (u | 0x80000000u);
            }
        }
    }

    // ---- 4-pass radix select: exact 32nd-largest key + tie quota ------------
    unsigned int prefix = 0, quota = KEEP;
    #pragma unroll
    for (int pass = 0; pass < 4; ++pass) {
        const int shift = 24 - 8 * pass;
        const unsigned int hs = (pass == 0) ? 0u : (unsigned int)(32 - 8 * pass);
        reinterpret_cast<uint4*>(hist[wave])[lane] = make_uint4(0u, 0u, 0u, 0u);
        __asm__ volatile("s_waitcnt lgkmcnt(0)" ::: "memory");
        #pragma unroll
        for (int e = 0; e < 64; ++e) {
            bool act = (pass == 0) || ((key[e] >> hs) == prefix);
            if (act) atomicAdd(&hist[wave][(key[e] >> shift) & 255u], 1u);
        }
        __asm__ volatile("s_waitcnt lgkmcnt(0)" ::: "memory");
        uint4 h = reinterpret_cast<const uint4*>(hist[wave])[lane];
        unsigned int s4  = h.x + h.y + h.z + h.w;
        unsigned int suf = s4;
        #pragma unroll
        for (int off = 1; off < 64; off <<= 1) {
            unsigned int v = (unsigned int)__shfl_down((int)suf, off);
            if (lane + off < 64) suf += v;
        }
        unsigned int above = suf - s4;
        bool cond = (suf >= quota) && (above < quota);
        unsigned int Bq = 0, nq = 0;
        if (cond) {
            unsigned int hb[4] = { h.x, h.y, h.z, h.w };
            unsigned int run = above;
            int Bj = 0;
            #pragma unroll
            for (int j = 3; j >= 0; --j) {
                unsigned int nb = run + hb[j];
                if (nb >= quota) { Bj = j; break; }
                run = nb;
            }
            Bq = (unsigned int)(lane * 4 + Bj);
            nq = quota - run;
        }
        unsigned long long bal = __ballot(cond);
        int src = __ffsll(bal) - 1;
        Bq = (unsigned int)__shfl((int)Bq, src);
        nq = (unsigned int)__shfl((int)nq, src);
        prefix = (prefix << 8) | Bq;
        quota  = nq;
    }
    const unsigned int T = prefix;
    const bool take_eq = (T != MASKED_KEY);

    // ---- compact selected (val,idx) into LDS --------------------------------
    if (lane < KEEP) { wsel[wave][lane] = 0.f; selIdx[wave][lane] = 0; }
    if (lane == 0)   { selCnt[wave] = 0; eqCnt[wave] = 0; }
    __asm__ volatile("s_waitcnt lgkmcnt(0)" ::: "memory");
    #pragma unroll
    for (int e = 0; e < 64; ++e) {
        unsigned int k = key[e];
        if (k > T) {
            int slot = atomicAdd(&selCnt[wave], 1);
            selKey[wave][slot] = k;
            selIdx[wave][slot] = 256 * (e >> 2) + 4 * lane + (e & 3);
        } else if (take_eq && k == T) {
            int t2 = atomicAdd(&eqCnt[wave], 1);
            if (t2 < (int)quota) {
                int slot = atomicAdd(&selCnt[wave], 1);
                selKey[wave][slot] = k;
                selIdx[wave][slot] = 256 * (e >> 2) + 4 * lane + (e & 3);
            }
        }
    }
    __asm__ volatile("s_waitcnt lgkmcnt(0)" ::: "memory");
    const int S = selCnt[wave];

    // ---- softmax over selected + padded static gather -----------------------
    if (S > 0) {
        float vj = -FLT_MAX;
        if (lane < S) {
            unsigned int kk = selKey[wave][lane];
            unsigned int u = (kk & 0x80000000u) ? (kk ^ 0x80000000u) : ~kk;
            vj = __uint_as_float(u);
        }
        float mx = vj;
        #pragma unroll
        for (int off = 1; off < 64; off <<= 1) mx = fmaxf(mx, __shfl_xor(mx, off));
        float e = (lane < S) ? expf(vj - mx) : 0.f;
        float sum = e;
        #pragma unroll
        for (int off = 1; off < 64; off <<= 1) sum += __shfl_xor(sum, off);
        if (lane < S) wsel[wave][lane] = e / sum;
        __asm__ volatile("s_waitcnt lgkmcnt(0)" ::: "memory");
        const float* vb = vmat + (size_t)b * LL * DD + lane;
        #pragma unroll
        for (int j = 0; j < KEEP; ++j) {
            float wj = wsel[wave][j];
            int   ij = selIdx[wave][j];
            o += wj * vb[(size_t)ij * DD];
        }
    }
    out[(size_t)row * DD + lane] = o;
}

// ============================================================================
// Fallback (proven round-1 monolith) in case ws_size < WS_TOTAL*4.
// ============================================================================
#define QT   2
#define NT   256
#define NTILES (LL / NT)

__global__ __launch_bounds__(NT, 4) void ga_fused_fb(
    const float* __restrict__ q, const float* __restrict__ kmat,
    const float* __restrict__ vmat, const int* __restrict__ mask,
    float* __restrict__ out)
{
    __shared__ float sc[QT][LL];
    __shared__ float q_s[QT][DD];
    __shared__ unsigned long long mbits[QT][LL / 64];
    __shared__ float redv[4][QT][DD];
    __shared__ float mean_s[QT][DD];
    __shared__ int   count_s[QT];
    __shared__ int   sel_idx[QT][KEEP];
    __shared__ float sel_val[QT][KEEP];
    __shared__ int   sel_cnt[QT];
    __shared__ float wred[4];
    __shared__ int   ired[4];
    __shared__ int   brk;
    __shared__ float wgt[QT][KEEP];

    const int t = threadIdx.x, wave = t >> 6, lane = t & 63;
    const int n0 = blockIdx.x * QT, b = n0 / LQ;

    if (t < QT) sel_cnt[t] = 0;
    if (t < QT * DD) q_s[t >> 6][t & 63] = q[(size_t)(n0 + (t >> 6)) * DD + (t & 63)];
    __syncthreads();

    const float4* q4_0 = reinterpret_cast<const float4*>(&q_s[0][0]);
    const float4* q4_1 = reinterpret_cast<const float4*>(&q_s[1][0]);
    for (int tile = 0; tile < NTILES; ++tile) {
        int l = tile * NT + t;
        const float4* kr = reinterpret_cast<const float4*>(kmat + (size_t)(b * LL + l) * DD);
        float d0 = 0.f, d1 = 0.f;
        #pragma unroll
        for (int i = 0; i < 16; ++i) {
            float4 kk = kr[i], qa = q4_0[i], qb = q4_1[i];
            d0 += kk.x * qa.x + kk.y * qa.y + kk.z * qa.z + kk.w * qa.w;
            d1 += kk.x * qb.x + kk.y * qb.y + kk.z * qb.z + kk.w * qb.w;
        }
        int mv0 = mask[(size_t)n0 * LL + l];
        int mv1 = mask[(size_t)(n0 + 1) * LL + l];
        unsigned long long b0 = __ballot(mv0 != 0);
        unsigned long long b1 = __ballot(mv1 != 0);
        if (lane == 0) { mbits[0][tile * 4 + wave] = b0; mbits[1][tile * 4 + wave] = b1; }
        sc[0][l] = mv0 ? d0 * 0.125f : -FLT_MAX;
        sc[1][l] = mv1 ? d1 * 0.125f : -FLT_MAX;
    }
    __syncthreads();

    if (wave < QT) {
        int c = (int)__popcll(mbits[wave][lane]);
        for (int off = 32; off >= 1; off >>= 1) c += __shfl_down(c, off);
        if (lane == 0) count_s[wave] = c;
    }
    {
        float acc0 = 0.f, acc1 = 0.f;
        const int g = wave, d = lane;
        for (int wi = 0; wi < LL / 64; ++wi) {
            unsigned long long w0 = mbits[0][wi], w1 = mbits[1][wi];
            const float* vp = vmat + (size_t)(b * LL + wi * 64 + g) * DD + d;
            #pragma unroll 4
            for (int ii = 0; ii < 16; ++ii) {
                int sh = g + 4 * ii;
                float vv = vp[(size_t)(4 * ii) * DD];
                if ((w0 >> sh) & 1ULL) acc0 += vv;
                if ((w1 >> sh) & 1ULL) acc1 += vv;
            }
        }
        redv[g][0][d] = acc0; redv[g][1][d] = acc1;
    }
    __syncthreads();
    if (t < QT * DD) {
        int qt = t >> 6, dd = t & 63;
        float s2 = redv[0][qt][dd] + redv[1][qt][dd] + redv[2][qt][dd] + redv[3][qt][dd];
        int c = count_s[qt]; if (c < 1) c = 1;
        mean_s[qt][dd] = s2 / (float)c;
    }
    __syncthreads();

    for (int qt = 0; qt < QT; ++qt) {
        for (int s = 0; s < KEEP; ++s) {
            float m = -FLT_MAX; int mi = LL;
            for (int j = 0; j < NTILES; ++j) {
                int l = j * NT + t;
                float val = sc[qt][l];
                if (val > m) { m = val; mi = l; }
            }
            for (int off = 32; off >= 1; off >>= 1) {
                float ov = __shfl_down(m, off);
                int   oi = __shfl_down(mi, off);
                if (ov > m || (ov == m && oi < mi)) { m = ov; mi = oi; }
            }
            if (lane == 0) { wred[wave] = m; ired[wave] = mi; }
            __syncthreads();
            if (t == 0) {
                float bv = wred[0]; int bi = ired[0];
                for (int w2 = 1; w2 < 4; ++w2) {
                    float ov = wred[w2]; int oi = ired[w2];
                    if (ov > bv || (ov == bv && oi < bi)) { bv = ov; bi = oi; }
                }
                if (bv > -FLT_MAX) {
                    sel_idx[qt][s] = bi; sel_val[qt][s] = bv; sel_cnt[qt] = s + 1;
                    sc[qt][bi] = -FLT_MAX; brk = 0;
                } else brk = 1;
            }
            __syncthreads();
            if (brk) break;
        }
    }

    if (wave < QT) {
        int qt = wave, S = sel_cnt[qt];
        if (S > 0) {
            float mx = sel_val[qt][0];
            float e = 0.f;
            if (lane < S) e = expf(sel_val[qt][lane] - mx);
            float ssum = e;
            for (int off = 32; off >= 1; off >>= 1) ssum += __shfl_xor(ssum, off);
            if (lane < S) wgt[qt][lane] = e / ssum;
        }
    }
    __syncthreads();
    if (wave < QT) {
        int qt = wave, S = sel_cnt[qt];
        float o = mean_s[qt][lane];
        for (int j = 0; j < S; ++j)
            o += wgt[qt][j] * vmat[(size_t)(b * LL + sel_idx[qt][j]) * DD + lane];
        out[(size_t)(n0 + qt) * DD + lane] = o;
    }
}

// ============================================================================
extern "C" void kernel_launch(void* const* d_in, const int* in_sizes, int n_in,
                              void* d_out, int out_size, void* d_ws, size_t ws_size,
                              hipStream_t stream) {
    const float* q    = (const float*)d_in[0];
    const float* kmat = (const float*)d_in[1];
    const float* vmat = (const float*)d_in[2];
    const int*   mask = (const int*)d_in[3];
    float* out = (float*)d_out;

    const size_t need = (size_t)WS_TOTAL * sizeof(float);   // 71.37 MB (== proven)
    if (ws_size >= need) {
        float* ws = (float*)d_ws;
        unsigned short* vt = (unsigned short*)(ws + WS_VT);
        float* pcnt = ws + WS_PC;
        // 3 graph nodes: k_vt (also zeroes out+pcnt) -> fused k_scores -> k_select
        hipLaunchKernelGGL(k_vt, dim3(NB * 16), dim3(256), 0, stream,
                           vmat, vt, out, pcnt);
        hipLaunchKernelGGL(k_scores, dim3(4096), dim3(256), 0, stream,
                           q, kmat, mask, vt, ws, out, pcnt);
        hipLaunchKernelGGL(k_select, dim3(NROWS / 4), dim3(256), 0, stream,
                           vmat, ws, pcnt, out);
    } else {
        hipLaunchKernelGGL(ga_fused_fb, dim3(NROWS / QT), dim3(NT), 0, stream,
                           q, kmat, vmat, mask, out);
    }
}

// Round 13
// 251.106 us; speedup vs baseline: 1.0904x; 1.0904x over previous
//
#include <hip/hip_runtime.h>
#include <float.h>
#include <math.h>

// Problem constants (from reference setup_inputs)
#define LQ   512
#define LL   4096      // key length
#define DD   64        // d_qk == d_v
#define KEEP 32        // MAX_SET_SIZE
#define NB   8         // batches
#define NROWS (NB * LQ)    // 4096 flat query rows

// ---- ws layout (floats) -----------------------------------------------------
// scores : [NROWS][LL] fp32                67.11 MB
// VT     : [NB][DD][LL] bf16                4.19 MB
// pcnt   : [NROWS] fp32 counts (atomic)     0.02 MB (region sized 4x, proven)
#define WS_VT    (NROWS * LL)                    // 16,777,216
#define WS_PC    (WS_VT + (NB * DD * LL) / 2)    // 17,825,792
#define WS_TOTAL (WS_PC + 4 * NROWS)             // 17,842,176 floats = 71.37 MB

#define MASKED_KEY 0x00800000u              // order-key of -FLT_MAX

typedef short  bf16x8 __attribute__((ext_vector_type(8)));
typedef float  f32x4  __attribute__((ext_vector_type(4)));

__device__ __forceinline__ float dot4(float4 a, float4 b) {
    return a.x * b.x + a.y * b.y + a.z * b.z + a.w * b.w;
}
__device__ __forceinline__ unsigned short f2bf(float f) {
    unsigned int u = __float_as_uint(f);
    return (unsigned short)((u + 0x7FFFu + ((u >> 16) & 1u)) >> 16);   // RNE
}

// ============================================================================
// P0: v[b][l][d] fp32 -> VT[b][d][l] bf16 (LDS tile transpose) + ZERO out and
// pcnt (absorbs memset nodes). VERBATIM R11 (control).
// ============================================================================
#define TP_LB 256
__global__ __launch_bounds__(256) void k_vt(
    const float* __restrict__ v, unsigned short* __restrict__ vt,
    float* __restrict__ out, float* __restrict__ pcnt)
{
    __shared__ unsigned short tile[DD][TP_LB + 8];   // +8 ushorts: bank de-phase
    const int t  = threadIdx.x;
    const int b  = blockIdx.x >> 4;                  // 16 blocks per batch
    const int l0 = (blockIdx.x & 15) * TP_LB;

    // ---- zeroing (replaces memset nodes): 128 blocks cover out + pcnt ------
    {
        float4 z4 = {0.f, 0.f, 0.f, 0.f};
        float4* oz = reinterpret_cast<float4*>(out);  // 65536 float4 total
        oz[blockIdx.x * 512 + t]       = z4;
        oz[blockIdx.x * 512 + 256 + t] = z4;
        if (t < 32) pcnt[blockIdx.x * 32 + t] = 0.f;  // 128*32 = 4096
    }

    const float4* vg = reinterpret_cast<const float4*>(v + ((size_t)b * LL + l0) * DD);
    #pragma unroll
    for (int i = 0; i < 16; ++i) {
        int j = t + 256 * i;                         // f4 index: l = j>>4, dq = (j&15)*4
        float4 f = vg[j];
        int l = j >> 4, dq = (j & 15) * 4;
        tile[dq + 0][l] = f2bf(f.x);
        tile[dq + 1][l] = f2bf(f.y);
        tile[dq + 2][l] = f2bf(f.z);
        tile[dq + 3][l] = f2bf(f.w);
    }
    __syncthreads();
    const int d = t >> 2, seg = t & 3;               // 64 ushorts per thread
    const uint4* src = reinterpret_cast<const uint4*>(&tile[d][seg * 64]);
    uint4* dst = reinterpret_cast<uint4*>(vt + ((size_t)b * DD + d) * LL + l0 + seg * 64);
    #pragma unroll
    for (int i = 0; i < 8; ++i) dst[i] = src[i];
}

// ============================================================================
// K1 v5: register-K scores + fused masked-mean partial.
// = R10/R11 proven form (kreg loaded AT scoring start — the R12 early-hoist
// regressed: compiler refused the live range across the barrier, VGPR stayed
// 64, VALUBusy fell 35->29) with ONE retained change from R12:
//   sums padded [16][17] — independently confirmed by counter to halve
//   SQ_LDS_BANK_CONFLICT (1.05M -> 524K).
// ============================================================================
__global__ __launch_bounds__(256) void k_scores(
    const float* __restrict__ q,
    const float* __restrict__ kmat,
    const int*   __restrict__ mask,
    const unsigned short* __restrict__ vt,
    float*       __restrict__ ws_sc,
    float*       __restrict__ out,
    float*       __restrict__ pcnt)
{
    __shared__ unsigned long long bits64[4][16];     // [wave][row] 512 B
    __shared__ float sums[4][4][16][17];             // padded: bank de-phase
    __shared__ float cnt_s[4][16];

    const int t    = threadIdx.x;
    const int wave = t >> 6;
    const int lane = t & 63;
    const int lc   = blockIdx.x & 15;                // l-chunk -> XCD spread (%8)
    const int rg   = blockIdx.x >> 4;                // row-group 0..255
    const int n0   = rg * 16;
    const int b    = n0 / LQ;
    const int l    = lc * 256 + wave * 64 + lane;    // this lane's l

    // ---- mask prefetch: 16 rows, coalesced dword each -----------------------
    int mreg[16];
    #pragma unroll
    for (int p = 0; p < 16; ++p)
        mreg[p] = mask[(size_t)(n0 + p) * LL + l];

    // ---- ballots -> per-row 64-bit masks of this wave's 64 l ---------------
    unsigned long long bl[16];
    #pragma unroll
    for (int p = 0; p < 16; ++p) bl[p] = __ballot(mreg[p] != 0);
    if (lane == 0) {
        #pragma unroll
        for (int p = 0; p < 16; ++p) bits64[wave][p] = bl[p];
    }
    __asm__ volatile("s_waitcnt lgkmcnt(0)" ::: "memory");

    // ---- fused mean partial: 8 MFMA off LDS bits + VT ----------------------
    {
        const int row_a = lane & 15;                 // MFMA m / B n index
        const int chunk = lane >> 4;                 // k-quad
        const unsigned char* bb =
            reinterpret_cast<const unsigned char*>(&bits64[wave][row_a]);
        const unsigned short* vtb =
            vt + (size_t)b * DD * LL + lc * 256 + wave * 64 + chunk * 8;

        f32x4 acc[4];
        #pragma unroll
        for (int dt = 0; dt < 4; ++dt) acc[dt] = (f32x4){0.f, 0.f, 0.f, 0.f};

        #pragma unroll
        for (int s = 0; s < 2; ++s) {                // K-step: 32 l each
            const unsigned int byte = bb[s * 4 + chunk];
            unsigned int pk[4];
            pk[0] = ((byte & 1u)   ? 0x3F80u : 0u) | ((byte & 2u)   ? 0x3F800000u : 0u);
            pk[1] = ((byte & 4u)   ? 0x3F80u : 0u) | ((byte & 8u)   ? 0x3F800000u : 0u);
            pk[2] = ((byte & 16u)  ? 0x3F80u : 0u) | ((byte & 32u)  ? 0x3F800000u : 0u);
            pk[3] = ((byte & 64u)  ? 0x3F80u : 0u) | ((byte & 128u) ? 0x3F800000u : 0u);
            bf16x8 afrag = *reinterpret_cast<bf16x8*>(pk);
            #pragma unroll
            for (int dt = 0; dt < 4; ++dt) {
                bf16x8 bfrag = *reinterpret_cast<const bf16x8*>(
                    vtb + (size_t)(dt * 16 + row_a) * LL + s * 32);
                acc[dt] = __builtin_amdgcn_mfma_f32_16x16x32_bf16(afrag, bfrag, acc[dt], 0, 0, 0);
            }
        }
        #pragma unroll
        for (int dt = 0; dt < 4; ++dt)
            #pragma unroll
            for (int r = 0; r < 4; ++r)
                sums[wave][dt][chunk * 4 + r][row_a] = acc[dt][r];
        if (lane < 16)
            cnt_s[wave][lane] = (float)__popcll(bits64[wave][lane]);
    }
    __syncthreads();

    // ---- combine 4 waves + atomic partial accumulate ------------------------
    {
        const int d = t & 63, rgrp = t >> 6;
        #pragma unroll
        for (int rr = 0; rr < 4; ++rr) {
            const int row = rgrp * 4 + rr;
            float s = sums[0][d >> 4][row][d & 15] + sums[1][d >> 4][row][d & 15]
                    + sums[2][d >> 4][row][d & 15] + sums[3][d >> 4][row][d & 15];
            atomicAdd(&out[(size_t)(n0 + row) * DD + d], s);
        }
        if (t < 16) {
            float c = cnt_s[0][t] + cnt_s[1][t] + cnt_s[2][t] + cnt_s[3][t];
            atomicAdd(&pcnt[n0 + t], c);
        }
    }

    // ---- scoring: register-K, R9 proven form --------------------------------
    const float4* kr = reinterpret_cast<const float4*>(kmat + ((size_t)b * LL + l) * DD);
    float4 kreg[16];
    #pragma unroll
    for (int i = 0; i < 16; ++i) kreg[i] = kr[i];

    const int qb = __builtin_amdgcn_readfirstlane(n0 * DD);
    #pragma unroll
    for (int p = 0; p < 16; ++p) {
        const float4* qp = reinterpret_cast<const float4*>(q + qb + p * DD);
        float ax = 0.f, ay = 0.f, az = 0.f, aw = 0.f;
        #pragma unroll
        for (int i = 0; i < 16; ++i) {
            float4 qv = qp[i];                       // wave-uniform -> s_load
            ax = fmaf(qv.x, kreg[i].x, ax);
            ay = fmaf(qv.y, kreg[i].y, ay);
            az = fmaf(qv.z, kreg[i].z, az);
            aw = fmaf(qv.w, kreg[i].w, aw);
        }
        float acc = ax + ay + az + aw;
        ws_sc[(size_t)(n0 + p) * LL + l] = mreg[p] ? acc * 0.125f : -FLT_MAX;
    }
}

// ============================================================================
// K2: per-wave exact radix top-32 — VERBATIM R10/R11 (control).
// ============================================================================
__global__ __launch_bounds__(256, 3) void k_select(
    const float* __restrict__ vmat,
    const float* __restrict__ ws,
    const float* __restrict__ pcnt,
    float*       __restrict__ out)
{
    __shared__ unsigned int hist[4][256];
    __shared__ unsigned int selKey[4][KEEP];
    __shared__ int          selIdx[4][KEEP];
    __shared__ float        wsel[4][KEEP];
    __shared__ int          selCnt[4], eqCnt[4];

    const int t    = threadIdx.x;
    const int wave = t >> 6;
    const int lane = t & 63;
    const int row  = blockIdx.x * 4 + wave;
    const int b    = row / LQ;

    // ---- mean finalize: sum (atomic-accumulated) / clip(count,1) ------------
    float o = out[(size_t)row * DD + lane];
    {
        float cc = pcnt[row];
        if (cc < 1.f) cc = 1.f;
        o /= cc;
    }

    // ---- load row scores -> order-preserving uint keys (64 VGPRs) -----------
    unsigned int key[64];
    {
        const float4* sg = reinterpret_cast<const float4*>(ws) + (size_t)row * (LL / 4);
        #pragma unroll
        for (int i = 0; i < 16; ++i) {
            float4 f = sg[lane + 64 * i];
            float vals[4] = { f.x, f.y, f.z, f.w };
            #pragma unroll
            for (int c = 0; c < 4; ++c) {
                unsigned int u = __float_as_uint(vals[c]);
                key[4 * i + c] = ((int)u < 0) ? ~u : (u | 0x80000000u);
            }
        }
    }

    // ---- 4-pass radix select: exact 32nd-largest key + tie quota ------------
    unsigned int prefix = 0, quota = KEEP;
    #pragma unroll
    for (int pass = 0; pass < 4; ++pass) {
        const int shift = 24 - 8 * pass;
        const unsigned int hs = (pass == 0) ? 0u : (unsigned int)(32 - 8 * pass);
        reinterpret_cast<uint4*>(hist[wave])[lane] = make_uint4(0u, 0u, 0u, 0u);
        __asm__ volatile("s_waitcnt lgkmcnt(0)" ::: "memory");
        #pragma unroll
        for (int e = 0; e < 64; ++e) {
            bool act = (pass == 0) || ((key[e] >> hs) == prefix);
            if (act) atomicAdd(&hist[wave][(key[e] >> shift) & 255u], 1u);
        }
        __asm__ volatile("s_waitcnt lgkmcnt(0)" ::: "memory");
        uint4 h = reinterpret_cast<const uint4*>(hist[wave])[lane];
        unsigned int s4  = h.x + h.y + h.z + h.w;
        unsigned int suf = s4;
        #pragma unroll
        for (int off = 1; off < 64; off <<= 1) {
            unsigned int v = (unsigned int)__shfl_down((int)suf, off);
            if (lane + off < 64) suf += v;
        }
        unsigned int above = suf - s4;
        bool cond = (suf >= quota) && (above < quota);
        unsigned int Bq = 0, nq = 0;
        if (cond) {
            unsigned int hb[4] = { h.x, h.y, h.z, h.w };
            unsigned int run = above;
            int Bj = 0;
            #pragma unroll
            for (int j = 3; j >= 0; --j) {
                unsigned int nb = run + hb[j];
                if (nb >= quota) { Bj = j; break; }
                run = nb;
            }
            Bq = (unsigned int)(lane * 4 + Bj);
            nq = quota - run;
        }
        unsigned long long bal = __ballot(cond);
        int src = __ffsll(bal) - 1;
        Bq = (unsigned int)__shfl((int)Bq, src);
        nq = (unsigned int)__shfl((int)nq, src);
        prefix = (prefix << 8) | Bq;
        quota  = nq;
    }
    const unsigned int T = prefix;
    const bool take_eq = (T != MASKED_KEY);

    // ---- compact selected (val,idx) into LDS --------------------------------
    if (lane < KEEP) { wsel[wave][lane] = 0.f; selIdx[wave][lane] = 0; }
    if (lane == 0)   { selCnt[wave] = 0; eqCnt[wave] = 0; }
    __asm__ volatile("s_waitcnt lgkmcnt(0)" ::: "memory");
    #pragma unroll
    for (int e = 0; e < 64; ++e) {
        unsigned int k = key[e];
        if (k > T) {
            int slot = atomicAdd(&selCnt[wave], 1);
            selKey[wave][slot] = k;
            selIdx[wave][slot] = 256 * (e >> 2) + 4 * lane + (e & 3);
        } else if (take_eq && k == T) {
            int t2 = atomicAdd(&eqCnt[wave], 1);
            if (t2 < (int)quota) {
                int slot = atomicAdd(&selCnt[wave], 1);
                selKey[wave][slot] = k;
                selIdx[wave][slot] = 256 * (e >> 2) + 4 * lane + (e & 3);
            }
        }
    }
    __asm__ volatile("s_waitcnt lgkmcnt(0)" ::: "memory");
    const int S = selCnt[wave];

    // ---- softmax over selected + padded static gather -----------------------
    if (S > 0) {
        float vj = -FLT_MAX;
        if (lane < S) {
            unsigned int kk = selKey[wave][lane];
            unsigned int u = (kk & 0x80000000u) ? (kk ^ 0x80000000u) : ~kk;
            vj = __uint_as_float(u);
        }
        float mx = vj;
        #pragma unroll
        for (int off = 1; off < 64; off <<= 1) mx = fmaxf(mx, __shfl_xor(mx, off));
        float e = (lane < S) ? expf(vj - mx) : 0.f;
        float sum = e;
        #pragma unroll
        for (int off = 1; off < 64; off <<= 1) sum += __shfl_xor(sum, off);
        if (lane < S) wsel[wave][lane] = e / sum;
        __asm__ volatile("s_waitcnt lgkmcnt(0)" ::: "memory");
        const float* vb = vmat + (size_t)b * LL * DD + lane;
        #pragma unroll
        for (int j = 0; j < KEEP; ++j) {
            float wj = wsel[wave][j];
            int   ij = selIdx[wave][j];
            o += wj * vb[(size_t)ij * DD];
        }
    }
    out[(size_t)row * DD + lane] = o;
}

// ============================================================================
// Fallback (proven round-1 monolith) in case ws_size < WS_TOTAL*4.
// ============================================================================
#define QT   2
#define NT   256
#define NTILES (LL / NT)

__global__ __launch_bounds__(NT, 4) void ga_fused_fb(
    const float* __restrict__ q, const float* __restrict__ kmat,
    const float* __restrict__ vmat, const int* __restrict__ mask,
    float* __restrict__ out)
{
    __shared__ float sc[QT][LL];
    __shared__ float q_s[QT][DD];
    __shared__ unsigned long long mbits[QT][LL / 64];
    __shared__ float redv[4][QT][DD];
    __shared__ float mean_s[QT][DD];
    __shared__ int   count_s[QT];
    __shared__ int   sel_idx[QT][KEEP];
    __shared__ float sel_val[QT][KEEP];
    __shared__ int   sel_cnt[QT];
    __shared__ float wred[4];
    __shared__ int   ired[4];
    __shared__ int   brk;
    __shared__ float wgt[QT][KEEP];

    const int t = threadIdx.x, wave = t >> 6, lane = t & 63;
    const int n0 = blockIdx.x * QT, b = n0 / LQ;

    if (t < QT) sel_cnt[t] = 0;
    if (t < QT * DD) q_s[t >> 6][t & 63] = q[(size_t)(n0 + (t >> 6)) * DD + (t & 63)];
    __syncthreads();

    const float4* q4_0 = reinterpret_cast<const float4*>(&q_s[0][0]);
    const float4* q4_1 = reinterpret_cast<const float4*>(&q_s[1][0]);
    for (int tile = 0; tile < NTILES; ++tile) {
        int l = tile * NT + t;
        const float4* kr = reinterpret_cast<const float4*>(kmat + (size_t)(b * LL + l) * DD);
        float d0 = 0.f, d1 = 0.f;
        #pragma unroll
        for (int i = 0; i < 16; ++i) {
            float4 kk = kr[i], qa = q4_0[i], qb = q4_1[i];
            d0 += kk.x * qa.x + kk.y * qa.y + kk.z * qa.z + kk.w * qa.w;
            d1 += kk.x * qb.x + kk.y * qb.y + kk.z * qb.z + kk.w * qb.w;
        }
        int mv0 = mask[(size_t)n0 * LL + l];
        int mv1 = mask[(size_t)(n0 + 1) * LL + l];
        unsigned long long b0 = __ballot(mv0 != 0);
        unsigned long long b1 = __ballot(mv1 != 0);
        if (lane == 0) { mbits[0][tile * 4 + wave] = b0; mbits[1][tile * 4 + wave] = b1; }
        sc[0][l] = mv0 ? d0 * 0.125f : -FLT_MAX;
        sc[1][l] = mv1 ? d1 * 0.125f : -FLT_MAX;
    }
    __syncthreads();

    if (wave < QT) {
        int c = (int)__popcll(mbits[wave][lane]);
        for (int off = 32; off >= 1; off >>= 1) c += __shfl_down(c, off);
        if (lane == 0) count_s[wave] = c;
    }
    {
        float acc0 = 0.f, acc1 = 0.f;
        const int g = wave, d = lane;
        for (int wi = 0; wi < LL / 64; ++wi) {
            unsigned long long w0 = mbits[0][wi], w1 = mbits[1][wi];
            const float* vp = vmat + (size_t)(b * LL + wi * 64 + g) * DD + d;
            #pragma unroll 4
            for (int ii = 0; ii < 16; ++ii) {
                int sh = g + 4 * ii;
                float vv = vp[(size_t)(4 * ii) * DD];
                if ((w0 >> sh) & 1ULL) acc0 += vv;
                if ((w1 >> sh) & 1ULL) acc1 += vv;
            }
        }
        redv[g][0][d] = acc0; redv[g][1][d] = acc1;
    }
    __syncthreads();
    if (t < QT * DD) {
        int qt = t >> 6, dd = t & 63;
        float s2 = redv[0][qt][dd] + redv[1][qt][dd] + redv[2][qt][dd] + redv[3][qt][dd];
        int c = count_s[qt]; if (c < 1) c = 1;
        mean_s[qt][dd] = s2 / (float)c;
    }
    __syncthreads();

    for (int qt = 0; qt < QT; ++qt) {
        for (int s = 0; s < KEEP; ++s) {
            float m = -FLT_MAX; int mi = LL;
            for (int j = 0; j < NTILES; ++j) {
                int l = j * NT + t;
                float val = sc[qt][l];
                if (val > m) { m = val; mi = l; }
            }
            for (int off = 32; off >= 1; off >>= 1) {
                float ov = __shfl_down(m, off);
                int   oi = __shfl_down(mi, off);
                if (ov > m || (ov == m && oi < mi)) { m = ov; mi = oi; }
            }
            if (lane == 0) { wred[wave] = m; ired[wave] = mi; }
            __syncthreads();
            if (t == 0) {
                float bv = wred[0]; int bi = ired[0];
                for (int w2 = 1; w2 < 4; ++w2) {
                    float ov = wred[w2]; int oi = ired[w2];
                    if (ov > bv || (ov == bv && oi < bi)) { bv = ov; bi = oi; }
                }
                if (bv > -FLT_MAX) {
                    sel_idx[qt][s] = bi; sel_val[qt][s] = bv; sel_cnt[qt] = s + 1;
                    sc[qt][bi] = -FLT_MAX; brk = 0;
                } else brk = 1;
            }
            __syncthreads();
            if (brk) break;
        }
    }

    if (wave < QT) {
        int qt = wave, S = sel_cnt[qt];
        if (S > 0) {
            float mx = sel_val[qt][0];
            float e = 0.f;
            if (lane < S) e = expf(sel_val[qt][lane] - mx);
            float ssum = e;
            for (int off = 32; off >= 1; off >>= 1) ssum += __shfl_xor(ssum, off);
            if (lane < S) wgt[qt][lane] = e / ssum;
        }
    }
    __syncthreads();
    if (wave < QT) {
        int qt = wave, S = sel_cnt[qt];
        float o = mean_s[qt][lane];
        for (int j = 0; j < S; ++j)
            o += wgt[qt][j] * vmat[(size_t)(b * LL + sel_idx[qt][j]) * DD + lane];
        out[(size_t)(n0 + qt) * DD + lane] = o;
    }
}

// ============================================================================
extern "C" void kernel_launch(void* const* d_in, const int* in_sizes, int n_in,
                              void* d_out, int out_size, void* d_ws, size_t ws_size,
                              hipStream_t stream) {
    const float* q    = (const float*)d_in[0];
    const float* kmat = (const float*)d_in[1];
    const float* vmat = (const float*)d_in[2];
    const int*   mask = (const int*)d_in[3];
    float* out = (float*)d_out;

    const size_t need = (size_t)WS_TOTAL * sizeof(float);   // 71.37 MB (== proven)
    if (ws_size >= need) {
        float* ws = (float*)d_ws;
        unsigned short* vt = (unsigned short*)(ws + WS_VT);
        float* pcnt = ws + WS_PC;
        // 3 graph nodes: k_vt (also zeroes out+pcnt) -> fused k_scores -> k_select
        hipLaunchKernelGGL(k_vt, dim3(NB * 16), dim3(256), 0, stream,
                           vmat, vt, out, pcnt);
        hipLaunchKernelGGL(k_scores, dim3(4096), dim3(256), 0, stream,
                           q, kmat, mask, vt, ws, out, pcnt);
        hipLaunchKernelGGL(k_select, dim3(NROWS / 4), dim3(256), 0, stream,
                           vmat, ws, pcnt, out);
    } else {
        hipLaunchKernelGGL(ga_fused_fb, dim3(NROWS / QT), dim3(NT), 0, stream,
                           q, kmat, vmat, mask, out);
    }
}

// Round 14
// 247.753 us; speedup vs baseline: 1.1052x; 1.0135x over previous
//
#include <hip/hip_runtime.h>
#include <float.h>
#include <math.h>

// Problem constants (from reference setup_inputs)
#define LQ   512
#define LL   4096      // key length
#define DD   64        // d_qk == d_v
#define KEEP 32        // MAX_SET_SIZE
#define NB   8         // batches
#define NROWS (NB * LQ)    // 4096 flat query rows

// ---- ws layout (floats) -----------------------------------------------------
// scores : [NROWS][LL] fp32                67.11 MB
// VT     : [NB][DD][LL] bf16                4.19 MB
// pcnt   : [NROWS] fp32 counts (atomic)     0.02 MB (region sized 4x, proven)
#define WS_VT    (NROWS * LL)                    // 16,777,216
#define WS_PC    (WS_VT + (NB * DD * LL) / 2)    // 17,825,792
#define WS_TOTAL (WS_PC + 4 * NROWS)             // 17,842,176 floats = 71.37 MB

#define MASKED_KEY 0x00800000u              // order-key of -FLT_MAX

typedef short  bf16x8 __attribute__((ext_vector_type(8)));
typedef float  f32x4  __attribute__((ext_vector_type(4)));

__device__ __forceinline__ float dot4(float4 a, float4 b) {
    return a.x * b.x + a.y * b.y + a.z * b.z + a.w * b.w;
}
__device__ __forceinline__ unsigned short f2bf(float f) {
    unsigned int u = __float_as_uint(f);
    return (unsigned short)((u + 0x7FFFu + ((u >> 16) & 1u)) >> 16);   // RNE
}

// ============================================================================
// P0: v[b][l][d] fp32 -> VT[b][d][l] bf16 (LDS tile transpose) + ZERO out and
// pcnt (absorbs memset nodes; 3 graph nodes total). VERBATIM R11 (best: 249us).
// ============================================================================
#define TP_LB 256
__global__ __launch_bounds__(256) void k_vt(
    const float* __restrict__ v, unsigned short* __restrict__ vt,
    float* __restrict__ out, float* __restrict__ pcnt)
{
    __shared__ unsigned short tile[DD][TP_LB + 8];   // +8 ushorts: bank de-phase
    const int t  = threadIdx.x;
    const int b  = blockIdx.x >> 4;                  // 16 blocks per batch
    const int l0 = (blockIdx.x & 15) * TP_LB;

    // ---- zeroing (replaces memset nodes): 128 blocks cover out + pcnt ------
    {
        float4 z4 = {0.f, 0.f, 0.f, 0.f};
        float4* oz = reinterpret_cast<float4*>(out);  // 65536 float4 total
        oz[blockIdx.x * 512 + t]       = z4;
        oz[blockIdx.x * 512 + 256 + t] = z4;
        if (t < 32) pcnt[blockIdx.x * 32 + t] = 0.f;  // 128*32 = 4096
    }

    const float4* vg = reinterpret_cast<const float4*>(v + ((size_t)b * LL + l0) * DD);
    #pragma unroll
    for (int i = 0; i < 16; ++i) {
        int j = t + 256 * i;                         // f4 index: l = j>>4, dq = (j&15)*4
        float4 f = vg[j];
        int l = j >> 4, dq = (j & 15) * 4;
        tile[dq + 0][l] = f2bf(f.x);
        tile[dq + 1][l] = f2bf(f.y);
        tile[dq + 2][l] = f2bf(f.z);
        tile[dq + 3][l] = f2bf(f.w);
    }
    __syncthreads();
    const int d = t >> 2, seg = t & 3;               // 64 ushorts per thread
    const uint4* src = reinterpret_cast<const uint4*>(&tile[d][seg * 64]);
    uint4* dst = reinterpret_cast<uint4*>(vt + ((size_t)b * DD + d) * LL + l0 + seg * 64);
    #pragma unroll
    for (int i = 0; i < 8; ++i) dst[i] = src[i];
}

// ============================================================================
// K1: register-K scores + fused masked-mean partial. VERBATIM R11 (best
// measured config, 96-97us). Session findings baked into this form:
//  - register-K scoring (R9): lane = one l-column, K row in 16 float4 VGPRs,
//    q via wave-uniform scalar loads -> 112us (LDS-staged) became 70us.
//  - mean fused via ballot-bits -> bf16 MFMA vs VT (R10): deletes the k_mean
//    kernel and its 67 MB second mask read; mean rides at +26us.
//  - kreg loaded AT scoring start: R12's early-hoist regressed (compiler
//    refuses the live range across the barrier; VALUBusy 35->29).
//  - sums NOT padded: R13 showed the pad halves bank conflicts but is
//    time-neutral (LDS-write stall not on critical path); this matches the
//    best-measured binary exactly.
// ============================================================================
__global__ __launch_bounds__(256) void k_scores(
    const float* __restrict__ q,
    const float* __restrict__ kmat,
    const int*   __restrict__ mask,
    const unsigned short* __restrict__ vt,
    float*       __restrict__ ws_sc,
    float*       __restrict__ out,
    float*       __restrict__ pcnt)
{
    __shared__ unsigned long long bits64[4][16];     // [wave][row] 512 B
    __shared__ float sums[4][4][16][16];             // [wave][dtile][row][col] 16 KB
    __shared__ float cnt_s[4][16];

    const int t    = threadIdx.x;
    const int wave = t >> 6;
    const int lane = t & 63;
    const int lc   = blockIdx.x & 15;                // l-chunk -> XCD spread (%8)
    const int rg   = blockIdx.x >> 4;                // row-group 0..255
    const int n0   = rg * 16;
    const int b    = n0 / LQ;
    const int l    = lc * 256 + wave * 64 + lane;    // this lane's l

    // ---- mask prefetch: 16 rows, coalesced dword each -----------------------
    int mreg[16];
    #pragma unroll
    for (int p = 0; p < 16; ++p)
        mreg[p] = mask[(size_t)(n0 + p) * LL + l];

    // ---- ballots -> per-row 64-bit masks of this wave's 64 l ---------------
    unsigned long long bl[16];
    #pragma unroll
    for (int p = 0; p < 16; ++p) bl[p] = __ballot(mreg[p] != 0);
    if (lane == 0) {
        #pragma unroll
        for (int p = 0; p < 16; ++p) bits64[wave][p] = bl[p];
    }
    __asm__ volatile("s_waitcnt lgkmcnt(0)" ::: "memory");

    // ---- fused mean partial: 8 MFMA off LDS bits + VT ----------------------
    {
        const int row_a = lane & 15;                 // MFMA m / B n index
        const int chunk = lane >> 4;                 // k-quad
        const unsigned char* bb =
            reinterpret_cast<const unsigned char*>(&bits64[wave][row_a]);
        const unsigned short* vtb =
            vt + (size_t)b * DD * LL + lc * 256 + wave * 64 + chunk * 8;

        f32x4 acc[4];
        #pragma unroll
        for (int dt = 0; dt < 4; ++dt) acc[dt] = (f32x4){0.f, 0.f, 0.f, 0.f};

        #pragma unroll
        for (int s = 0; s < 2; ++s) {                // K-step: 32 l each
            const unsigned int byte = bb[s * 4 + chunk];
            unsigned int pk[4];
            pk[0] = ((byte & 1u)   ? 0x3F80u : 0u) | ((byte & 2u)   ? 0x3F800000u : 0u);
            pk[1] = ((byte & 4u)   ? 0x3F80u : 0u) | ((byte & 8u)   ? 0x3F800000u : 0u);
            pk[2] = ((byte & 16u)  ? 0x3F80u : 0u) | ((byte & 32u)  ? 0x3F800000u : 0u);
            pk[3] = ((byte & 64u)  ? 0x3F80u : 0u) | ((byte & 128u) ? 0x3F800000u : 0u);
            bf16x8 afrag = *reinterpret_cast<bf16x8*>(pk);
            #pragma unroll
            for (int dt = 0; dt < 4; ++dt) {
                bf16x8 bfrag = *reinterpret_cast<const bf16x8*>(
                    vtb + (size_t)(dt * 16 + row_a) * LL + s * 32);
                acc[dt] = __builtin_amdgcn_mfma_f32_16x16x32_bf16(afrag, bfrag, acc[dt], 0, 0, 0);
            }
        }
        #pragma unroll
        for (int dt = 0; dt < 4; ++dt)
            #pragma unroll
            for (int r = 0; r < 4; ++r)
                sums[wave][dt][chunk * 4 + r][row_a] = acc[dt][r];
        if (lane < 16)
            cnt_s[wave][lane] = (float)__popcll(bits64[wave][lane]);
    }
    __syncthreads();

    // ---- combine 4 waves + atomic partial accumulate ------------------------
    {
        const int d = t & 63, rgrp = t >> 6;
        #pragma unroll
        for (int rr = 0; rr < 4; ++rr) {
            const int row = rgrp * 4 + rr;
            float s = sums[0][d >> 4][row][d & 15] + sums[1][d >> 4][row][d & 15]
                    + sums[2][d >> 4][row][d & 15] + sums[3][d >> 4][row][d & 15];
            atomicAdd(&out[(size_t)(n0 + row) * DD + d], s);
        }
        if (t < 16) {
            float c = cnt_s[0][t] + cnt_s[1][t] + cnt_s[2][t] + cnt_s[3][t];
            atomicAdd(&pcnt[n0 + t], c);
        }
    }

    // ---- scoring: register-K, R9 proven form --------------------------------
    const float4* kr = reinterpret_cast<const float4*>(kmat + ((size_t)b * LL + l) * DD);
    float4 kreg[16];
    #pragma unroll
    for (int i = 0; i < 16; ++i) kreg[i] = kr[i];

    const int qb = __builtin_amdgcn_readfirstlane(n0 * DD);
    #pragma unroll
    for (int p = 0; p < 16; ++p) {
        const float4* qp = reinterpret_cast<const float4*>(q + qb + p * DD);
        float ax = 0.f, ay = 0.f, az = 0.f, aw = 0.f;
        #pragma unroll
        for (int i = 0; i < 16; ++i) {
            float4 qv = qp[i];                       // wave-uniform -> s_load
            ax = fmaf(qv.x, kreg[i].x, ax);
            ay = fmaf(qv.y, kreg[i].y, ay);
            az = fmaf(qv.z, kreg[i].z, az);
            aw = fmaf(qv.w, kreg[i].w, aw);
        }
        float acc = ax + ay + az + aw;
        ws_sc[(size_t)(n0 + p) * LL + l] = mreg[p] ? acc * 0.125f : -FLT_MAX;
    }
}

// ============================================================================
// K2: per-wave exact radix top-32 + mean finalize. VERBATIM R11 (best).
// ============================================================================
__global__ __launch_bounds__(256, 3) void k_select(
    const float* __restrict__ vmat,
    const float* __restrict__ ws,
    const float* __restrict__ pcnt,
    float*       __restrict__ out)
{
    __shared__ unsigned int hist[4][256];
    __shared__ unsigned int selKey[4][KEEP];
    __shared__ int          selIdx[4][KEEP];
    __shared__ float        wsel[4][KEEP];
    __shared__ int          selCnt[4], eqCnt[4];

    const int t    = threadIdx.x;
    const int wave = t >> 6;
    const int lane = t & 63;
    const int row  = blockIdx.x * 4 + wave;
    const int b    = row / LQ;

    // ---- mean finalize: sum (atomic-accumulated) / clip(count,1) ------------
    float o = out[(size_t)row * DD + lane];
    {
        float cc = pcnt[row];
        if (cc < 1.f) cc = 1.f;
        o /= cc;
    }

    // ---- load row scores -> order-preserving uint keys (64 VGPRs) -----------
    unsigned int key[64];
    {
        const float4* sg = reinterpret_cast<const float4*>(ws) + (size_t)row * (LL / 4);
        #pragma unroll
        for (int i = 0; i < 16; ++i) {
            float4 f = sg[lane + 64 * i];
            float vals[4] = { f.x, f.y, f.z, f.w };
            #pragma unroll
            for (int c = 0; c < 4; ++c) {
                unsigned int u = __float_as_uint(vals[c]);
                key[4 * i + c] = ((int)u < 0) ? ~u : (u | 0x80000000u);
            }
        }
    }

    // ---- 4-pass radix select: exact 32nd-largest key + tie quota ------------
    unsigned int prefix = 0, quota = KEEP;
    #pragma unroll
    for (int pass = 0; pass < 4; ++pass) {
        const int shift = 24 - 8 * pass;
        const unsigned int hs = (pass == 0) ? 0u : (unsigned int)(32 - 8 * pass);
        reinterpret_cast<uint4*>(hist[wave])[lane] = make_uint4(0u, 0u, 0u, 0u);
        __asm__ volatile("s_waitcnt lgkmcnt(0)" ::: "memory");
        #pragma unroll
        for (int e = 0; e < 64; ++e) {
            bool act = (pass == 0) || ((key[e] >> hs) == prefix);
            if (act) atomicAdd(&hist[wave][(key[e] >> shift) & 255u], 1u);
        }
        __asm__ volatile("s_waitcnt lgkmcnt(0)" ::: "memory");
        uint4 h = reinterpret_cast<const uint4*>(hist[wave])[lane];
        unsigned int s4  = h.x + h.y + h.z + h.w;
        unsigned int suf = s4;
        #pragma unroll
        for (int off = 1; off < 64; off <<= 1) {
            unsigned int v = (unsigned int)__shfl_down((int)suf, off);
            if (lane + off < 64) suf += v;
        }
        unsigned int above = suf - s4;
        bool cond = (suf >= quota) && (above < quota);
        unsigned int Bq = 0, nq = 0;
        if (cond) {
            unsigned int hb[4] = { h.x, h.y, h.z, h.w };
            unsigned int run = above;
            int Bj = 0;
            #pragma unroll
            for (int j = 3; j >= 0; --j) {
                unsigned int nb = run + hb[j];
                if (nb >= quota) { Bj = j; break; }
                run = nb;
            }
            Bq = (unsigned int)(lane * 4 + Bj);
            nq = quota - run;
        }
        unsigned long long bal = __ballot(cond);
        int src = __ffsll(bal) - 1;
        Bq = (unsigned int)__shfl((int)Bq, src);
        nq = (unsigned int)__shfl((int)nq, src);
        prefix = (prefix << 8) | Bq;
        quota  = nq;
    }
    const unsigned int T = prefix;
    const bool take_eq = (T != MASKED_KEY);

    // ---- compact selected (val,idx) into LDS --------------------------------
    if (lane < KEEP) { wsel[wave][lane] = 0.f; selIdx[wave][lane] = 0; }
    if (lane == 0)   { selCnt[wave] = 0; eqCnt[wave] = 0; }
    __asm__ volatile("s_waitcnt lgkmcnt(0)" ::: "memory");
    #pragma unroll
    for (int e = 0; e < 64; ++e) {
        unsigned int k = key[e];
        if (k > T) {
            int slot = atomicAdd(&selCnt[wave], 1);
            selKey[wave][slot] = k;
            selIdx[wave][slot] = 256 * (e >> 2) + 4 * lane + (e & 3);
        } else if (take_eq && k == T) {
            int t2 = atomicAdd(&eqCnt[wave], 1);
            if (t2 < (int)quota) {
                int slot = atomicAdd(&selCnt[wave], 1);
                selKey[wave][slot] = k;
                selIdx[wave][slot] = 256 * (e >> 2) + 4 * lane + (e & 3);
            }
        }
    }
    __asm__ volatile("s_waitcnt lgkmcnt(0)" ::: "memory");
    const int S = selCnt[wave];

    // ---- softmax over selected + padded static gather -----------------------
    if (S > 0) {
        float vj = -FLT_MAX;
        if (lane < S) {
            unsigned int kk = selKey[wave][lane];
            unsigned int u = (kk & 0x80000000u) ? (kk ^ 0x80000000u) : ~kk;
            vj = __uint_as_float(u);
        }
        float mx = vj;
        #pragma unroll
        for (int off = 1; off < 64; off <<= 1) mx = fmaxf(mx, __shfl_xor(mx, off));
        float e = (lane < S) ? expf(vj - mx) : 0.f;
        float sum = e;
        #pragma unroll
        for (int off = 1; off < 64; off <<= 1) sum += __shfl_xor(sum, off);
        if (lane < S) wsel[wave][lane] = e / sum;
        __asm__ volatile("s_waitcnt lgkmcnt(0)" ::: "memory");
        const float* vb = vmat + (size_t)b * LL * DD + lane;
        #pragma unroll
        for (int j = 0; j < KEEP; ++j) {
            float wj = wsel[wave][j];
            int   ij = selIdx[wave][j];
            o += wj * vb[(size_t)ij * DD];
        }
    }
    out[(size_t)row * DD + lane] = o;
}

// ============================================================================
// Fallback (proven round-1 monolith) in case ws_size < WS_TOTAL*4.
// ============================================================================
#define QT   2
#define NT   256
#define NTILES (LL / NT)

__global__ __launch_bounds__(NT, 4) void ga_fused_fb(
    const float* __restrict__ q, const float* __restrict__ kmat,
    const float* __restrict__ vmat, const int* __restrict__ mask,
    float* __restrict__ out)
{
    __shared__ float sc[QT][LL];
    __shared__ float q_s[QT][DD];
    __shared__ unsigned long long mbits[QT][LL / 64];
    __shared__ float redv[4][QT][DD];
    __shared__ float mean_s[QT][DD];
    __shared__ int   count_s[QT];
    __shared__ int   sel_idx[QT][KEEP];
    __shared__ float sel_val[QT][KEEP];
    __shared__ int   sel_cnt[QT];
    __shared__ float wred[4];
    __shared__ int   ired[4];
    __shared__ int   brk;
    __shared__ float wgt[QT][KEEP];

    const int t = threadIdx.x, wave = t >> 6, lane = t & 63;
    const int n0 = blockIdx.x * QT, b = n0 / LQ;

    if (t < QT) sel_cnt[t] = 0;
    if (t < QT * DD) q_s[t >> 6][t & 63] = q[(size_t)(n0 + (t >> 6)) * DD + (t & 63)];
    __syncthreads();

    const float4* q4_0 = reinterpret_cast<const float4*>(&q_s[0][0]);
    const float4* q4_1 = reinterpret_cast<const float4*>(&q_s[1][0]);
    for (int tile = 0; tile < NTILES; ++tile) {
        int l = tile * NT + t;
        const float4* kr = reinterpret_cast<const float4*>(kmat + (size_t)(b * LL + l) * DD);
        float d0 = 0.f, d1 = 0.f;
        #pragma unroll
        for (int i = 0; i < 16; ++i) {
            float4 kk = kr[i], qa = q4_0[i], qb = q4_1[i];
            d0 += kk.x * qa.x + kk.y * qa.y + kk.z * qa.z + kk.w * qa.w;
            d1 += kk.x * qb.x + kk.y * qb.y + kk.z * qb.z + kk.w * qb.w;
        }
        int mv0 = mask[(size_t)n0 * LL + l];
        int mv1 = mask[(size_t)(n0 + 1) * LL + l];
        unsigned long long b0 = __ballot(mv0 != 0);
        unsigned long long b1 = __ballot(mv1 != 0);
        if (lane == 0) { mbits[0][tile * 4 + wave] = b0; mbits[1][tile * 4 + wave] = b1; }
        sc[0][l] = mv0 ? d0 * 0.125f : -FLT_MAX;
        sc[1][l] = mv1 ? d1 * 0.125f : -FLT_MAX;
    }
    __syncthreads();

    if (wave < QT) {
        int c = (int)__popcll(mbits[wave][lane]);
        for (int off = 32; off >= 1; off >>= 1) c += __shfl_down(c, off);
        if (lane == 0) count_s[wave] = c;
    }
    {
        float acc0 = 0.f, acc1 = 0.f;
        const int g = wave, d = lane;
        for (int wi = 0; wi < LL / 64; ++wi) {
            unsigned long long w0 = mbits[0][wi], w1 = mbits[1][wi];
            const float* vp = vmat + (size_t)(b * LL + wi * 64 + g) * DD + d;
            #pragma unroll 4
            for (int ii = 0; ii < 16; ++ii) {
                int sh = g + 4 * ii;
                float vv = vp[(size_t)(4 * ii) * DD];
                if ((w0 >> sh) & 1ULL) acc0 += vv;
                if ((w1 >> sh) & 1ULL) acc1 += vv;
            }
        }
        redv[g][0][d] = acc0; redv[g][1][d] = acc1;
    }
    __syncthreads();
    if (t < QT * DD) {
        int qt = t >> 6, dd = t & 63;
        float s2 = redv[0][qt][dd] + redv[1][qt][dd] + redv[2][qt][dd] + redv[3][qt][dd];
        int c = count_s[qt]; if (c < 1) c = 1;
        mean_s[qt][dd] = s2 / (float)c;
    }
    __syncthreads();

    for (int qt = 0; qt < QT; ++qt) {
        for (int s = 0; s < KEEP; ++s) {
            float m = -FLT_MAX; int mi = LL;
            for (int j = 0; j < NTILES; ++j) {
                int l = j * NT + t;
                float val = sc[qt][l];
                if (val > m) { m = val; mi = l; }
            }
            for (int off = 32; off >= 1; off >>= 1) {
                float ov = __shfl_down(m, off);
                int   oi = __shfl_down(mi, off);
                if (ov > m || (ov == m && oi < mi)) { m = ov; mi = oi; }
            }
            if (lane == 0) { wred[wave] = m; ired[wave] = mi; }
            __syncthreads();
            if (t == 0) {
                float bv = wred[0]; int bi = ired[0];
                for (int w2 = 1; w2 < 4; ++w2) {
                    float ov = wred[w2]; int oi = ired[w2];
                    if (ov > bv || (ov == bv && oi < bi)) { bv = ov; bi = oi; }
                }
                if (bv > -FLT_MAX) {
                    sel_idx[qt][s] = bi; sel_val[qt][s] = bv; sel_cnt[qt] = s + 1;
                    sc[qt][bi] = -FLT_MAX; brk = 0;
                } else brk = 1;
            }
            __syncthreads();
            if (brk) break;
        }
    }

    if (wave < QT) {
        int qt = wave, S = sel_cnt[qt];
        if (S > 0) {
            float mx = sel_val[qt][0];
            float e = 0.f;
            if (lane < S) e = expf(sel_val[qt][lane] - mx);
            float ssum = e;
            for (int off = 32; off >= 1; off >>= 1) ssum += __shfl_xor(ssum, off);
            if (lane < S) wgt[qt][lane] = e / ssum;
        }
    }
    __syncthreads();
    if (wave < QT) {
        int qt = wave, S = sel_cnt[qt];
        float o = mean_s[qt][lane];
        for (int j = 0; j < S; ++j)
            o += wgt[qt][j] * vmat[(size_t)(b * LL + sel_idx[qt][j]) * DD + lane];
        out[(size_t)(n0 + qt) * DD + lane] = o;
    }
}

// ============================================================================
extern "C" void kernel_launch(void* const* d_in, const int* in_sizes, int n_in,
                              void* d_out, int out_size, void* d_ws, size_t ws_size,
                              hipStream_t stream) {
    const float* q    = (const float*)d_in[0];
    const float* kmat = (const float*)d_in[1];
    const float* vmat = (const float*)d_in[2];
    const int*   mask = (const int*)d_in[3];
    float* out = (float*)d_out;

    const size_t need = (size_t)WS_TOTAL * sizeof(float);   // 71.37 MB (== proven)
    if (ws_size >= need) {
        float* ws = (float*)d_ws;
        unsigned short* vt = (unsigned short*)(ws + WS_VT);
        float* pcnt = ws + WS_PC;
        // 3 graph nodes: k_vt (also zeroes out+pcnt) -> fused k_scores -> k_select
        hipLaunchKernelGGL(k_vt, dim3(NB * 16), dim3(256), 0, stream,
                           vmat, vt, out, pcnt);
        hipLaunchKernelGGL(k_scores, dim3(4096), dim3(256), 0, stream,
                           q, kmat, mask, vt, ws, out, pcnt);
        hipLaunchKernelGGL(k_select, dim3(NROWS / 4), dim3(256), 0, stream,
                           vmat, ws, pcnt, out);
    } else {
        hipLaunchKernelGGL(ga_fused_fb, dim3(NROWS / QT), dim3(NT), 0, stream,
                           q, kmat, vmat, mask, out);
    }
}